// Round 10
// baseline (410.823 us; speedup 1.0000x reference)
//
#include <hip/hip_runtime.h>
#include <hip/hip_bf16.h>

#define NS 200000
#define KF 9
#define CC 64
#define RPB 64                 // rows per block (4 waves x 16 rows)
#define NB (NS / RPB)          // 3125 exact, no tail

typedef __bf16 bf16_t;
typedef __bf16 bf16x8 __attribute__((ext_vector_type(8)));
typedef __bf16 bf16x4 __attribute__((ext_vector_type(4)));
typedef float f32x4 __attribute__((ext_vector_type(4)));

// ---------------- combined prep: x->bf16, pack W1/W2, zero stats+zrow ----------------
__global__ void k_prep(const float* __restrict__ x, const float* __restrict__ W1,
                       const float* __restrict__ W2, bf16_t* __restrict__ xb,
                       bf16_t* __restrict__ W1p, bf16_t* __restrict__ W2p,
                       float* __restrict__ stats /*256*/, float* __restrict__ zrow /*32*/) {
  const int b = blockIdx.x;
  const int tid = threadIdx.x;
  if (b < 12500) {
    if (b == 0) {          // one-time zeroing
      stats[tid] = 0.f;    // 256 floats
      if (tid < 32) zrow[tid] = 0.f;
    }
    long base = ((long)b * 256 + tid) * 4;
    const float4 v = *(const float4*)(x + base);
    bf16x4 o;
    o[0] = (bf16_t)v.x; o[1] = (bf16_t)v.y; o[2] = (bf16_t)v.z; o[3] = (bf16_t)v.w;
    *(bf16x4*)(xb + base) = o;
    return;
  }
  int b2 = b - 12500;
  const float* W = (b2 < 144) ? W1 : W2;
  bf16_t* Wp = (b2 < 144) ? W1p : W2p;
  if (b2 >= 144) b2 -= 144;
  int p = b2 * 256 + tid;           // [0, 36864)
  int j = p & 7;
  int lane = (p >> 3) & 63;
  int kstep = (p >> 9) & 1;
  int ntile = (p >> 10) & 3;
  int k = p >> 12;
  int col = ntile * 16 + (lane & 15);
  int kk = kstep * 32 + 8 * (lane >> 4) + j;
  Wp[p] = (bf16_t)W[(k * CC + kk) * CC + col];
}

// ---------------- conv: wave-private LDS gather ring (depth-2) + optional fused BN1+ReLU
// Wave wid owns rows [row0+16*wid, +16). Per k: 2x global_load_lds (16B/lane) stage the
// wave's 16 rows x 128B into ring slot k%3 (global chunk pre-XOR-swizzled, LDS linear,
// ds_read re-applies the XOR -> conflict-free). vmcnt(4/2/0) counts ONLY our stage ops:
// safe under any compiler placement of the B loads (foreign ops merely over-wait).
template <int FUSE_BN>
__global__ __launch_bounds__(256, 4) void k_conv(
    const bf16_t* __restrict__ xsrc,  // NS x 64 bf16 gather source
    const int* __restrict__ nbr,      // NS x 9  (value NS == "no neighbor")
    const bf16_t* __restrict__ Wp,    // packed 9*4096 bf16
    bf16_t* __restrict__ y,           // NS x 64 bf16 conv out (raw)
    float* __restrict__ stats_out,    // [128]: sum | sumsq
    const float* __restrict__ stats_in,  // BN coeffs source (FUSE_BN)
    const float* __restrict__ gamma, const float* __restrict__ beta,
    const char* __restrict__ zrow)    // 128B zeros (sentinel gather target)
{
  __shared__ __align__(16) char Aring[4 * 3 * 2048];   // [wave][slot][16 rows x 128B]
  __shared__ int nbr_s[RPB * KF];                      // 576 ints
  __shared__ float lred[8 * CC];
  __shared__ __align__(16) bf16_t ssb[128];            // bf16 BN coeffs (FUSE_BN)

  const int tid = threadIdx.x;
  const int lane = tid & 63;
  const int wid = tid >> 6;
  const int row0 = blockIdx.x * RPB;
  const int l15 = lane & 15;
  const int lhi = lane >> 4;

  {
    const int* src = nbr + (long)row0 * KF;
    nbr_s[tid] = src[tid];
    nbr_s[tid + 256] = src[tid + 256];
    if (tid < 64) nbr_s[tid + 512] = src[tid + 512];
  }
  if (FUSE_BN) {
    if (tid < 64) {
      const float invN = 1.0f / (float)NS;
      float mean = stats_in[tid] * invN;
      float var = fmaxf(stats_in[64 + tid] * invN - mean * mean, 0.f);
      float rs = rsqrtf(var + 1e-5f);
      float sc = gamma[tid] * rs;
      ssb[tid] = (bf16_t)sc;
      ssb[64 + tid] = (bf16_t)(beta[tid] - mean * sc);
    }
  }
  __syncthreads();

  const char* xbb = (const char*)xsrc;
  char* ringw = Aring + wid * 6144;
  const int sgrp = lane >> 3;               // staging row group 0..7
  const int schunk = (lane & 7) ^ sgrp;     // pre-swizzled global chunk

  // stage the wave's 16 rows for offset k into ring slot s (2 x 1KB, linear LDS dest)
  auto stageA = [&](int s, int k) {
#pragma unroll
    for (int i = 0; i < 2; ++i) {
      int rloc = 8 * i + sgrp;                                  // local row 0..15
      unsigned u = (unsigned)nbr_s[(16 * wid + rloc) * KF + k];
      const char* gp = (u < NS) ? (xbb + (size_t)u * 128u + schunk * 16)
                                : (zrow + schunk * 16);
      __builtin_amdgcn_global_load_lds(
          (const __attribute__((address_space(1))) void*)gp,
          (__attribute__((address_space(3))) void*)(ringw + s * 2048 + i * 1024),
          16, 0, 0);
    }
  };

  const bf16x8* wp = (const bf16x8*)Wp;
  f32x4 acc[4];
#pragma unroll
  for (int n = 0; n < 4; ++n) acc[n] = (f32x4){0.f, 0.f, 0.f, 0.f};

  bf16x8 cB[4][2], nB[4][2];
  bf16x8 scb0, shb0, scb1, shb1;
  if (FUSE_BN) {
    scb0 = *(const bf16x8*)&ssb[8 * lhi];
    shb0 = *(const bf16x8*)&ssb[64 + 8 * lhi];
    scb1 = *(const bf16x8*)&ssb[32 + 8 * lhi];
    shb1 = *(const bf16x8*)&ssb[96 + 8 * lhi];
  }

  // prologue: stage A(0), A(1); load B(0)
  stageA(0, 0);
  stageA(1, 1);
#pragma unroll
  for (int n = 0; n < 4; ++n)
#pragma unroll
    for (int kk = 0; kk < 2; ++kk)
      cB[n][kk] = wp[((0 * 4 + n) * 2 + kk) * 64 + lane];

#pragma unroll
  for (int k = 0; k < KF; ++k) {
    if (k + 1 < KF) {   // B(k+1) loads (L2-hot; compiler-managed)
#pragma unroll
      for (int n = 0; n < 4; ++n)
#pragma unroll
        for (int kk = 0; kk < 2; ++kk)
          nB[n][kk] = wp[(((k + 1) * 4 + n) * 2 + kk) * 64 + lane];
    }
    if (k + 2 < KF) stageA((k + 2) % 3, k + 2);   // depth-2 A prefetch
    // wait for A(k): allow our 4 newer stage ops (A(k+1),A(k+2)) to stay in flight
    if (k < KF - 2)       asm volatile("s_waitcnt vmcnt(4)" ::: "memory");
    else if (k == KF - 2) asm volatile("s_waitcnt vmcnt(2)" ::: "memory");
    else                  asm volatile("s_waitcnt vmcnt(0)" ::: "memory");
    __builtin_amdgcn_sched_barrier(0);

    const char* sb = ringw + (k % 3) * 2048;
    bf16x8 a0 = *(const bf16x8*)(sb + l15 * 128 + ((lhi ^ (l15 & 7)) * 16));
    bf16x8 a1 = *(const bf16x8*)(sb + l15 * 128 + (((4 + lhi) ^ (l15 & 7)) * 16));
    if (FUSE_BN) {
      float vm = ((unsigned)nbr_s[(16 * wid + l15) * KF + k] < NS) ? 1.f : 0.f;
#pragma unroll
      for (int j = 0; j < 8; ++j) {
        float f0 = (float)a0[j] * (float)scb0[j] + (float)shb0[j] * vm;
        a0[j] = (bf16_t)fmaxf(f0, 0.f);
        float f1 = (float)a1[j] * (float)scb1[j] + (float)shb1[j] * vm;
        a1[j] = (bf16_t)fmaxf(f1, 0.f);
      }
    }
    __builtin_amdgcn_s_setprio(1);
#pragma unroll
    for (int n = 0; n < 4; ++n)
      acc[n] = __builtin_amdgcn_mfma_f32_16x16x32_bf16(a0, cB[n][0], acc[n], 0, 0, 0);
#pragma unroll
    for (int n = 0; n < 4; ++n)
      acc[n] = __builtin_amdgcn_mfma_f32_16x16x32_bf16(a1, cB[n][1], acc[n], 0, 0, 0);
    __builtin_amdgcn_s_setprio(0);
#pragma unroll
    for (int n = 0; n < 4; ++n) { cB[n][0] = nB[n][0]; cB[n][1] = nB[n][1]; }
  }

  // epilogue: store y (bf16) + per-channel BN partials
  // C/D layout (m89): col = lane&15, row = 4*(lane>>4) + reg_idx
  float csum[4] = {0.f, 0.f, 0.f, 0.f}, csq[4] = {0.f, 0.f, 0.f, 0.f};
  const int rb0 = row0 + 16 * wid + 4 * lhi;
#pragma unroll
  for (int n = 0; n < 4; ++n) {
    const int col = 16 * n + l15;
#pragma unroll
    for (int j = 0; j < 4; ++j) {
      float v = acc[n][j];
      csum[n] += v; csq[n] += v * v;
      y[(long)(rb0 + j) * CC + col] = (bf16_t)v;
    }
  }
#pragma unroll
  for (int n = 0; n < 4; ++n) {
    csum[n] += __shfl_xor(csum[n], 16); csum[n] += __shfl_xor(csum[n], 32);
    csq[n]  += __shfl_xor(csq[n], 16);  csq[n]  += __shfl_xor(csq[n], 32);
  }
  if (lane < 16) {
#pragma unroll
    for (int n = 0; n < 4; ++n) {
      lred[wid * CC + 16 * n + l15] = csum[n];
      lred[4 * CC + wid * CC + 16 * n + l15] = csq[n];
    }
  }
  __syncthreads();
  if (tid < CC) {
    float s = lred[tid] + lred[CC + tid] + lred[2 * CC + tid] + lred[3 * CC + tid];
    float q = lred[4 * CC + tid] + lred[5 * CC + tid] + lred[6 * CC + tid] + lred[7 * CC + tid];
    atomicAdd(&stats_out[tid], s);
    atomicAdd(&stats_out[64 + tid], q);
  }
}

// ---------------- final: BN2 (from stats) + residual; o2 bf16 in ws -> fp32 d_out ----
__global__ void k_final(const bf16_t* __restrict__ o2b, const float* __restrict__ stats,
                        const float* __restrict__ gamma, const float* __restrict__ beta,
                        const float* __restrict__ x, float* __restrict__ out) {
  __shared__ float ss_s[128];
  const int tid = threadIdx.x;
  if (tid < 64) {
    const float invN = 1.0f / (float)NS;
    float mean = stats[tid] * invN;
    float var = fmaxf(stats[64 + tid] * invN - mean * mean, 0.f);
    float rs = rsqrtf(var + 1e-5f);
    float sc = gamma[tid] * rs;
    ss_s[tid] = sc;
    ss_s[64 + tid] = beta[tid] - mean * sc;
  }
  __syncthreads();
  long base = ((long)blockIdx.x * 256 + tid) * 4;
  bf16x4 v = *(const bf16x4*)(o2b + base);
  float4 f = *(const float4*)(x + base);
  int c0 = (int)(base & 63);
  float4 r;
  r.x = (float)v[0] * ss_s[c0 + 0] + ss_s[64 + c0 + 0] + f.x;
  r.y = (float)v[1] * ss_s[c0 + 1] + ss_s[64 + c0 + 1] + f.y;
  r.z = (float)v[2] * ss_s[c0 + 2] + ss_s[64 + c0 + 2] + f.z;
  r.w = (float)v[3] * ss_s[c0 + 3] + ss_s[64 + c0 + 3] + f.w;
  *(float4*)(out + base) = r;
}

extern "C" void kernel_launch(void* const* d_in, const int* in_sizes, int n_in,
                              void* d_out, int out_size, void* d_ws, size_t ws_size,
                              hipStream_t stream) {
  const float* features = (const float*)d_in[0];
  const int* nbr        = (const int*)d_in[1];
  const float* W1       = (const float*)d_in[2];
  const float* gamma1   = (const float*)d_in[3];
  const float* beta1    = (const float*)d_in[4];
  const float* W2       = (const float*)d_in[5];
  const float* gamma2   = (const float*)d_in[6];
  const float* beta2    = (const float*)d_in[7];

  // d_out as scratch: [xb bf16 | o1 bf16]; k_final rewrites d_out fully (fp32).
  bf16_t* xb = (bf16_t*)d_out;
  bf16_t* o1 = (bf16_t*)((char*)d_out + (size_t)NS * CC * 2);

  // d_ws: o2 bf16 (25.6MB) + packed weights + stats + zero row  (~25.9MB, proven fit)
  char* ws = (char*)d_ws;
  auto alignup = [](size_t x) { return (x + 255) & ~(size_t)255; };
  size_t off = 0;
  bf16_t* o2b = (bf16_t*)(ws + off); off += alignup((size_t)NS * CC * 2);
  bf16_t* W1p = (bf16_t*)(ws + off); off += alignup((size_t)KF * 4096 * 2);
  bf16_t* W2p = (bf16_t*)(ws + off); off += alignup((size_t)KF * 4096 * 2);
  float* stats = (float*)(ws + off); off += alignup(256 * 4);  // stats1|stats2
  float* zrow  = (float*)(ws + off); off += alignup(32 * 4);   // 128B zeros

  k_prep<<<12500 + 288, 256, 0, stream>>>(features, W1, W2, xb, W1p, W2p, stats, zrow);

  // conv1: gather xb -> o1 (raw bf16) + stats1
  k_conv<0><<<NB, 256, 0, stream>>>(xb, nbr, W1p, o1, stats,
                                    stats, gamma1, beta1, (const char*)zrow);
  // conv2: gather o1 with fused BN1+ReLU -> o2 (raw bf16, ws) + stats2
  k_conv<1><<<NB, 256, 0, stream>>>(o1, nbr, W2p, o2b, stats + 128,
                                    stats, gamma1, beta1, (const char*)zrow);
  // final: BN2 + residual -> fp32 out
  k_final<<<12500, 256, 0, stream>>>(o2b, stats + 128, gamma2, beta2, features, (float*)d_out);
}